// Round 4
// baseline (343.933 us; speedup 1.0000x reference)
//
#include <hip/hip_runtime.h>
#include <cstdint>
#include <cstddef>

// B=8,S=2048,E=512,FFN=2048,Q=8 -> fc2 GEMM: M=16384, N=512, K=2048.
// Fully fused, ZERO LDS, ZERO barriers in the K-loop.
// Key trick: feed fc1's MFMA row-PERMUTED W1 rows (f = 8*(r>>2)+(r&3), then +4)
// so the fc1 D-fragment, after relu+bf16 pack, is bit-identical to the fc2
// A-operand fragment (lane(fr,quad) holds act[m=fr][k=8*quad..8*quad+7]).
// b1 folded exactly: w1x[f][8] = b1[f], z-fragment carries 1.0 at k=8.

typedef __attribute__((ext_vector_type(8))) short s16x8;
typedef __attribute__((ext_vector_type(4))) float f32x4;

__device__ __forceinline__ unsigned short f2bf(float f) {  // RNE
  unsigned int u = __float_as_uint(f);
  unsigned int r = u + 0x7fffu + ((u >> 16) & 1u);
  return (unsigned short)(r >> 16);
}

// two fp32 -> packed bf16 dword (round-half-up; inputs finite)
__device__ __forceinline__ unsigned pk_bf16(float lo, float hi) {
  unsigned ul = __float_as_uint(lo) + 0x8000u;
  unsigned uh = __float_as_uint(hi) + 0x8000u;
  return __builtin_amdgcn_perm(uh, ul, 0x07060302u);  // [hi16(uh)|hi16(ul)]
}

__device__ __forceinline__ s16x8 u4s(uint4 u) {
  union { uint4 a; s16x8 b; } c; c.a = u; return c.b;
}

// ---------------------------------------------------------------------------
// Setup: bid<1024: w2 [512][2048] fp32 -> w2b bf16 (same layout).
//        bid>=1024: w1x [2048][32] bf16: cols 0..7 = w1 row, col 8 = b1[f],
//        cols 9..31 = 0 (zero-pad so quads 1..3 of the fc1 A-frag need no
//        masking — they just load zeros / the b1 slot).
// ---------------------------------------------------------------------------
__global__ __launch_bounds__(256) void k_cvt(const float* __restrict__ w2,
                                             const float* __restrict__ w1,
                                             const float* __restrict__ b1,
                                             unsigned short* __restrict__ w2b,
                                             unsigned short* __restrict__ w1x) {
  const int bid = blockIdx.x, t = threadIdx.x;
  if (bid < 1024) {
    size_t i = ((size_t)bid * 256 + t) * 4;
    float4 v = *(const float4*)(w2 + i);
    uint2 p;
    p.x = f2bf(v.x) | ((unsigned)f2bf(v.y) << 16);
    p.y = f2bf(v.z) | ((unsigned)f2bf(v.w) << 16);
    *(uint2*)(w2b + i) = p;
  } else {
    const int row = (bid - 1024) * 256 + t;  // 0..2047
    const float* wr = w1 + (size_t)row * 8;
    float4 a = *(const float4*)wr;
    float4 b = *(const float4*)(wr + 4);
    uint4 s0;
    s0.x = f2bf(a.x) | ((unsigned)f2bf(a.y) << 16);
    s0.y = f2bf(a.z) | ((unsigned)f2bf(a.w) << 16);
    s0.z = f2bf(b.x) | ((unsigned)f2bf(b.y) << 16);
    s0.w = f2bf(b.z) | ((unsigned)f2bf(b.w) << 16);
    uint4 s1 = {(unsigned)f2bf(b1[row]), 0u, 0u, 0u};
    uint4 zz = {0u, 0u, 0u, 0u};
    unsigned short* dst = w1x + (size_t)row * 32;
    *(uint4*)dst = s0;
    *(uint4*)(dst + 8) = s1;
    *(uint4*)(dst + 16) = zz;
    *(uint4*)(dst + 24) = zz;
  }
}

// ---------------------------------------------------------------------------
// Fused kernel. Block = 64m x 128n, 4 waves each owning 16m x 128n.
// Grid = (16384/64) * (512/128) = 1024 blocks (4/CU).
// Per kt (32 f): 2 fc1 MFMA (row-permuted W1) -> relu+pack -> A-frag,
// 8 fc2 MFMA with b-frags straight from L2-resident w2b. No LDS. No barriers.
// ---------------------------------------------------------------------------
__global__ __launch_bounds__(256) void k_fused(
    const float* __restrict__ x, const float* __restrict__ ry,
    const unsigned short* __restrict__ w1x,  // [2048][32]
    const unsigned short* __restrict__ w2b,  // [512][2048]
    const float* __restrict__ b2, float* __restrict__ out) {
  const int t = threadIdx.x;
  const int lane = t & 63;
  const int w = t >> 6;
  const int fr = lane & 15;
  const int quad = lane >> 4;
  const int mt = blockIdx.x >> 2;
  const int nt = blockIdx.x & 3;
  const int r0 = mt * 64;
  const int c0 = nt * 128;
  const int m0 = r0 + w * 16;  // wave's m-base

  // ---- z B-fragment (kt-invariant): lane(fr,quad) holds B[k=8q+j][m=fr]
  //   quad0: z[m][0..7]; quad1: {1.0, 0..} (the b1 slot); quads 2,3: 0.
  const float* xr = x + (size_t)(m0 + fr) * 512;
  float4 xa = *(const float4*)xr;
  float4 xb = *(const float4*)(xr + 4);
  float4 ra = *(const float4*)ry;
  float4 rb = *(const float4*)(ry + 4);
  unsigned zd0 = f2bf(__cosf(xa.x) * __cosf(ra.x)) |
                 ((unsigned)f2bf(__cosf(xa.y) * __cosf(ra.y)) << 16);
  unsigned zd1 = f2bf(__cosf(xa.z) * __cosf(ra.z)) |
                 ((unsigned)f2bf(__cosf(xa.w) * __cosf(ra.w)) << 16);
  unsigned zd2 = f2bf(__cosf(xb.x) * __cosf(rb.x)) |
                 ((unsigned)f2bf(__cosf(xb.y) * __cosf(rb.y)) << 16);
  unsigned zd3 = f2bf(__cosf(xb.z) * __cosf(rb.z)) |
                 ((unsigned)f2bf(__cosf(xb.w) * __cosf(rb.w)) << 16);
  uint4 bzu;
  bzu.x = (quad == 0) ? zd0 : ((quad == 1) ? 0x00003F80u : 0u);
  bzu.y = (quad == 0) ? zd1 : 0u;
  bzu.z = (quad == 0) ? zd2 : 0u;
  bzu.w = (quad == 0) ? zd3 : 0u;
  const s16x8 bz = u4s(bzu);

  // fc1 A pointer, row-permuted: MFMA#1 feeds row f = 8*(fr>>2)+(fr&3),
  // MFMA#2 the same +4 -> lane ends up with f = 8*quad + {0..7}.
  const int rowp = 8 * (fr >> 2) + (fr & 3);
  const unsigned short* gW = w1x + (size_t)rowp * 32 + quad * 8;

  // fc2 b-frag pointers: lane reads w2b[n=c0+j*16+fr][kt*32 + quad*8 .. +7]
  const unsigned short* gB[8];
#pragma unroll
  for (int j = 0; j < 8; ++j)
    gB[j] = w2b + (size_t)(c0 + j * 16 + fr) * 2048 + quad * 8;

  f32x4 acc[8];
#pragma unroll
  for (int j = 0; j < 8; ++j) acc[j] = (f32x4){0.f, 0.f, 0.f, 0.f};

  const f32x4 zero4 = (f32x4){0.f, 0.f, 0.f, 0.f};

#define MAKE_A(kt_, dst_)                                                     \
  {                                                                           \
    const unsigned short* p_ = gW + (size_t)(kt_)*1024; /* 32 rows * 32 */    \
    s16x8 aw1_ = *(const s16x8*)p_;                                           \
    s16x8 aw2_ = *(const s16x8*)(p_ + 128); /* +4 rows */                     \
    f32x4 p1_ = __builtin_amdgcn_mfma_f32_16x16x32_bf16(aw1_, bz, zero4, 0, 0, 0); \
    f32x4 p2_ = __builtin_amdgcn_mfma_f32_16x16x32_bf16(aw2_, bz, zero4, 0, 0, 0); \
    uint4 u_;                                                                 \
    u_.x = pk_bf16(fmaxf(p1_[0], 0.f), fmaxf(p1_[1], 0.f));                   \
    u_.y = pk_bf16(fmaxf(p1_[2], 0.f), fmaxf(p1_[3], 0.f));                   \
    u_.z = pk_bf16(fmaxf(p2_[0], 0.f), fmaxf(p2_[1], 0.f));                   \
    u_.w = pk_bf16(fmaxf(p2_[2], 0.f), fmaxf(p2_[3], 0.f));                   \
    dst_ = u4s(u_);                                                           \
  }

  s16x8 afrag;
  MAKE_A(0, afrag);

  for (int kt = 0; kt < 64; ++kt) {
    s16x8 bf[8];
#pragma unroll
    for (int j = 0; j < 8; ++j) bf[j] = *(const s16x8*)(gB[j] + kt * 32);
    const s16x8 acur = afrag;
    if (kt < 63) MAKE_A(kt + 1, afrag);  // overlaps fc2 below (no barriers)
#pragma unroll
    for (int j = 0; j < 8; ++j)
      acc[j] = __builtin_amdgcn_mfma_f32_16x16x32_bf16(acur, bf[j], acc[j],
                                                       0, 0, 0);
  }
#undef MAKE_A

  // epilogue: fc2 D: lane(fr,quad) holds D[m-local = quad*4+rr][n-local = fr]
  float bias[8];
#pragma unroll
  for (int j = 0; j < 8; ++j) bias[j] = b2[c0 + j * 16 + fr];
  const int mrow = m0 + quad * 4;
#pragma unroll
  for (int rr = 0; rr < 4; ++rr) {
    float* orow = out + (size_t)(mrow + rr) * 512 + c0;
#pragma unroll
    for (int j = 0; j < 8; ++j) orow[j * 16 + fr] = acc[j][rr] + bias[j];
  }
}

// ---------------------------------------------------------------------------
// Emergency fallback if ws < ~2.2 MB: fused fp32, 1 row/block (slow, correct).
// ---------------------------------------------------------------------------
__global__ __launch_bounds__(256) void k_naive(
    const float* __restrict__ x, const float* __restrict__ ry,
    const float* __restrict__ w1, const float* __restrict__ b1,
    const float* __restrict__ w2, const float* __restrict__ b2,
    float* __restrict__ out) {
  __shared__ float zsh[8];
  __shared__ float acts[2048];
  const int r = blockIdx.x;
  const int t = threadIdx.x;
  if (t < 8) zsh[t] = __cosf(x[(size_t)r * 512 + t]) * __cosf(ry[t]);
  __syncthreads();
  float z[8];
#pragma unroll
  for (int q = 0; q < 8; ++q) z[q] = zsh[q];
#pragma unroll
  for (int i = 0; i < 8; ++i) {
    const int f = t * 8 + i;
    const float* wr = w1 + (size_t)f * 8;
    float4 a = *(const float4*)wr;
    float4 b = *(const float4*)(wr + 4);
    float h = b1[f] + z[0] * a.x + z[1] * a.y + z[2] * a.z + z[3] * a.w +
              z[4] * b.x + z[5] * b.y + z[6] * b.z + z[7] * b.w;
    acts[f] = fmaxf(h, 0.0f);
  }
  __syncthreads();
  for (int ee = 0; ee < 2; ++ee) {
    const int e = t + ee * 256;
    const float* wr = w2 + (size_t)e * 2048;
    float acc = b2[e];
    for (int f = 0; f < 2048; f += 4) {
      float4 wv = *(const float4*)(wr + f);
      float4 av = *(const float4*)(acts + f);
      acc += av.x * wv.x + av.y * wv.y + av.z * wv.z + av.w * wv.w;
    }
    out[(size_t)r * 512 + e] = acc;
  }
}

extern "C" void kernel_launch(void* const* d_in, const int* in_sizes, int n_in,
                              void* d_out, int out_size, void* d_ws,
                              size_t ws_size, hipStream_t stream) {
  const float* x  = (const float*)d_in[0];
  const float* ry = (const float*)d_in[1];
  const float* w1 = (const float*)d_in[2];
  const float* b1 = (const float*)d_in[3];
  const float* w2 = (const float*)d_in[4];
  const float* b2 = (const float*)d_in[5];
  float* out = (float*)d_out;

  const size_t w2b_bytes = (size_t)512 * 2048 * 2;   // 2 MiB
  const size_t w1x_bytes = (size_t)2048 * 32 * 2;    // 128 KiB
  if (ws_size < w2b_bytes + w1x_bytes) {
    k_naive<<<dim3(16384), dim3(256), 0, stream>>>(x, ry, w1, b1, w2, b2, out);
    return;
  }

  unsigned short* w2b = (unsigned short*)d_ws;
  unsigned short* w1x = (unsigned short*)((char*)d_ws + w2b_bytes);

  k_cvt<<<dim3(1032), dim3(256), 0, stream>>>(w2, w1, b1, w2b, w1x);
  k_fused<<<dim3(1024), dim3(256), 0, stream>>>(x, ry, w1x, w2b, b2, out);
  (void)in_sizes; (void)n_in; (void)out_size;
}

// Round 5
// 232.753 us; speedup vs baseline: 1.4777x; 1.4777x over previous
//
#include <hip/hip_runtime.h>
#include <cstdint>
#include <cstddef>

// B=8,S=2048,E=512,FFN=2048,Q=8 -> fc2 GEMM: M=16384, N=512, K=2048.
// Fully fused, zero LDS, zero K-loop barriers (R4 trick, correctness-proven).
// R5 fix: weights pre-tiled into MFMA-fragment order so every fragment load is
// a contiguous, fully-coalesced 1-KB wave read (R4's 4-KB lane stride caused a
// 16x transaction storm + total L1 set aliasing -> 269 us).
//
// w2t[nt][kt][nl][quad][e]  (nt<4, kt<64, nl<128, quad<4, e<8) bf16, 2 MiB
//   = w2[nt*128+nl][kt*32+quad*8+e]
// w1t[kt][i][fr][quad][e]   (kt<64, i<2, fr<16, quad<4, e<8)  bf16, 128 KiB
//   = fc1 A-frag content for f = kt*32 + 8*(fr>>2)+(fr&3) + 4*i:
//     quad0 = w1[f][0..7], quad1 = {b1[f],0...}, quad2/3 = 0
//     (row permutation makes the fc1 D-frag bit-identical to fc2's A-frag)

typedef __attribute__((ext_vector_type(8))) short s16x8;
typedef __attribute__((ext_vector_type(4))) float f32x4;

__device__ __forceinline__ unsigned short f2bf(float f) {  // RNE
  unsigned int u = __float_as_uint(f);
  unsigned int r = u + 0x7fffu + ((u >> 16) & 1u);
  return (unsigned short)(r >> 16);
}

// two fp32 -> packed bf16 dword (round-half-up; inputs finite)
__device__ __forceinline__ unsigned pk_bf16(float lo, float hi) {
  unsigned ul = __float_as_uint(lo) + 0x8000u;
  unsigned uh = __float_as_uint(hi) + 0x8000u;
  return __builtin_amdgcn_perm(uh, ul, 0x07060302u);  // [hi16(uh)|hi16(ul)]
}

__device__ __forceinline__ s16x8 u4s(uint4 u) {
  union { uint4 a; s16x8 b; } c; c.a = u; return c.b;
}

// ---------------------------------------------------------------------------
// Setup/retile. bid<128: w2 -> w2t. bid>=128 (8 blocks): w1,b1 -> w1t.
// ---------------------------------------------------------------------------
__global__ __launch_bounds__(256) void k_cvt(const float* __restrict__ w2,
                                             const float* __restrict__ w1,
                                             const float* __restrict__ b1,
                                             unsigned short* __restrict__ w2t,
                                             unsigned short* __restrict__ w1t) {
  const int bid = blockIdx.x, t = threadIdx.x;
  if (bid < 128) {
    const int tid = bid * 256 + t;
    const int n = tid >> 6, kt = tid & 63;
    const float* src = w2 + (size_t)n * 2048 + kt * 32;
    unsigned short* dst =
        w2t + ((size_t)(n >> 7) * 64 + kt) * 4096 + (n & 127) * 32;
#pragma unroll
    for (int g = 0; g < 4; ++g) {
      float4 v0 = *(const float4*)(src + g * 8);
      float4 v1 = *(const float4*)(src + g * 8 + 4);
      uint4 p;
      p.x = f2bf(v0.x) | ((unsigned)f2bf(v0.y) << 16);
      p.y = f2bf(v0.z) | ((unsigned)f2bf(v0.w) << 16);
      p.z = f2bf(v1.x) | ((unsigned)f2bf(v1.y) << 16);
      p.w = f2bf(v1.z) | ((unsigned)f2bf(v1.w) << 16);
      *(uint4*)(dst + g * 8) = p;
    }
  } else {
    const int idx = (bid - 128) * 256 + t;  // 0..2047 = kt*32 + i*16 + fr
    const int kt = idx >> 5, rem = idx & 31, i = rem >> 4, fr = rem & 15;
    const int f = kt * 32 + 8 * (fr >> 2) + (fr & 3) + 4 * i;
    const float* wr = w1 + (size_t)f * 8;
    float4 a = *(const float4*)wr;
    float4 b = *(const float4*)(wr + 4);
    uint4 q0;
    q0.x = f2bf(a.x) | ((unsigned)f2bf(a.y) << 16);
    q0.y = f2bf(a.z) | ((unsigned)f2bf(a.w) << 16);
    q0.z = f2bf(b.x) | ((unsigned)f2bf(b.y) << 16);
    q0.w = f2bf(b.z) | ((unsigned)f2bf(b.w) << 16);
    uint4 q1 = {(unsigned)f2bf(b1[f]), 0u, 0u, 0u};
    uint4 zz = {0u, 0u, 0u, 0u};
    unsigned short* dst = w1t + (size_t)idx * 32;
    *(uint4*)dst = q0;
    *(uint4*)(dst + 8) = q1;
    *(uint4*)(dst + 16) = zz;
    *(uint4*)(dst + 24) = zz;
  }
}

// ---------------------------------------------------------------------------
// Fused kernel. Block = 64m x 128n, 4 waves each 16m x 128n. Grid 1024.
// bid -> mt = bid % 256 (XCD round-robin shares one B panel per XCD),
//        nt = bid / 256.
// ---------------------------------------------------------------------------
__global__ __launch_bounds__(256) void k_fused(
    const float* __restrict__ x, const float* __restrict__ ry,
    const unsigned short* __restrict__ w1t, const unsigned short* __restrict__ w2t,
    const float* __restrict__ b2, float* __restrict__ out) {
  const int t = threadIdx.x;
  const int lane = t & 63;
  const int w = t >> 6;
  const int fr = lane & 15;
  const int quad = lane >> 4;
  const int mt = blockIdx.x & 255;
  const int nt = blockIdx.x >> 8;
  const int c0 = nt * 128;
  const int m0 = mt * 64 + w * 16;  // wave's m-base

  // ---- z B-fragment (kt-invariant): lane(fr,quad) holds B[k=8q+j][m=fr]
  //   quad0: z[m][0..7]; quad1: {1.0, 0..} (b1 slot); quads 2,3: 0.
  const float* xr = x + (size_t)(m0 + fr) * 512;
  float4 xa = *(const float4*)xr;
  float4 xb = *(const float4*)(xr + 4);
  float4 ra = *(const float4*)ry;
  float4 rb = *(const float4*)(ry + 4);
  unsigned zd0 = f2bf(__cosf(xa.x) * __cosf(ra.x)) |
                 ((unsigned)f2bf(__cosf(xa.y) * __cosf(ra.y)) << 16);
  unsigned zd1 = f2bf(__cosf(xa.z) * __cosf(ra.z)) |
                 ((unsigned)f2bf(__cosf(xa.w) * __cosf(ra.w)) << 16);
  unsigned zd2 = f2bf(__cosf(xb.x) * __cosf(rb.x)) |
                 ((unsigned)f2bf(__cosf(xb.y) * __cosf(rb.y)) << 16);
  unsigned zd3 = f2bf(__cosf(xb.z) * __cosf(rb.z)) |
                 ((unsigned)f2bf(__cosf(xb.w) * __cosf(rb.w)) << 16);
  uint4 bzu;
  bzu.x = (quad == 0) ? zd0 : ((quad == 1) ? 0x00003F80u : 0u);
  bzu.y = (quad == 0) ? zd1 : 0u;
  bzu.z = (quad == 0) ? zd2 : 0u;
  bzu.w = (quad == 0) ? zd3 : 0u;
  const s16x8 bz = u4s(bzu);

  // fragment-ordered pointers: every load below is a contiguous 1-KB wave read
  const unsigned short* gW = w1t + fr * 32 + quad * 8;                  // +kt*1024
  const unsigned short* gB0 = w2t + (size_t)nt * 64 * 4096 + fr * 32 + quad * 8;
  const unsigned short* gB4 = gB0 + 2048;                               // j=4..7

  f32x4 acc[8];
#pragma unroll
  for (int j = 0; j < 8; ++j) acc[j] = (f32x4){0.f, 0.f, 0.f, 0.f};

  const f32x4 zero4 = (f32x4){0.f, 0.f, 0.f, 0.f};

#define MAKE_A(kt_, dst_)                                                      \
  {                                                                            \
    const unsigned short* p_ = gW + (size_t)(kt_) * 1024;                      \
    s16x8 aw1_ = *(const s16x8*)p_;                                            \
    s16x8 aw2_ = *(const s16x8*)(p_ + 512);                                    \
    f32x4 p1_ = __builtin_amdgcn_mfma_f32_16x16x32_bf16(aw1_, bz, zero4, 0, 0, 0); \
    f32x4 p2_ = __builtin_amdgcn_mfma_f32_16x16x32_bf16(aw2_, bz, zero4, 0, 0, 0); \
    uint4 u_;                                                                  \
    u_.x = pk_bf16(fmaxf(p1_[0], 0.f), fmaxf(p1_[1], 0.f));                    \
    u_.y = pk_bf16(fmaxf(p1_[2], 0.f), fmaxf(p1_[3], 0.f));                    \
    u_.z = pk_bf16(fmaxf(p2_[0], 0.f), fmaxf(p2_[1], 0.f));                    \
    u_.w = pk_bf16(fmaxf(p2_[2], 0.f), fmaxf(p2_[3], 0.f));                    \
    dst_ = u4s(u_);                                                            \
  }

  s16x8 afrag;
  MAKE_A(0, afrag);

  for (int kt = 0; kt < 64; ++kt) {
    const unsigned short* b0 = gB0 + (size_t)kt * 4096;
    const unsigned short* b4 = gB4 + (size_t)kt * 4096;
    s16x8 bf[8];
#pragma unroll
    for (int j = 0; j < 4; ++j) bf[j] = *(const s16x8*)(b0 + j * 512);
#pragma unroll
    for (int j = 0; j < 4; ++j) bf[4 + j] = *(const s16x8*)(b4 + j * 512);
    const s16x8 acur = afrag;
    if (kt < 63) MAKE_A(kt + 1, afrag);  // overlaps fc2 below
#pragma unroll
    for (int j = 0; j < 8; ++j)
      acc[j] = __builtin_amdgcn_mfma_f32_16x16x32_bf16(acur, bf[j], acc[j],
                                                       0, 0, 0);
  }
#undef MAKE_A

  // epilogue: fc2 D: lane(fr,quad) holds D[m-local=quad*4+rr][n-local=fr]
  float bias[8];
#pragma unroll
  for (int j = 0; j < 8; ++j) bias[j] = b2[c0 + j * 16 + fr];
  const int mrow = m0 + quad * 4;
#pragma unroll
  for (int rr = 0; rr < 4; ++rr) {
    float* orow = out + (size_t)(mrow + rr) * 512 + c0;
#pragma unroll
    for (int j = 0; j < 8; ++j) orow[j * 16 + fr] = acc[j][rr] + bias[j];
  }
}

// ---------------------------------------------------------------------------
// Emergency fallback if ws < ~2.2 MB: fused fp32, 1 row/block (slow, correct).
// ---------------------------------------------------------------------------
__global__ __launch_bounds__(256) void k_naive(
    const float* __restrict__ x, const float* __restrict__ ry,
    const float* __restrict__ w1, const float* __restrict__ b1,
    const float* __restrict__ w2, const float* __restrict__ b2,
    float* __restrict__ out) {
  __shared__ float zsh[8];
  __shared__ float acts[2048];
  const int r = blockIdx.x;
  const int t = threadIdx.x;
  if (t < 8) zsh[t] = __cosf(x[(size_t)r * 512 + t]) * __cosf(ry[t]);
  __syncthreads();
  float z[8];
#pragma unroll
  for (int q = 0; q < 8; ++q) z[q] = zsh[q];
#pragma unroll
  for (int i = 0; i < 8; ++i) {
    const int f = t * 8 + i;
    const float* wr = w1 + (size_t)f * 8;
    float4 a = *(const float4*)wr;
    float4 b = *(const float4*)(wr + 4);
    float h = b1[f] + z[0] * a.x + z[1] * a.y + z[2] * a.z + z[3] * a.w +
              z[4] * b.x + z[5] * b.y + z[6] * b.z + z[7] * b.w;
    acts[f] = fmaxf(h, 0.0f);
  }
  __syncthreads();
  for (int ee = 0; ee < 2; ++ee) {
    const int e = t + ee * 256;
    const float* wr = w2 + (size_t)e * 2048;
    float acc = b2[e];
    for (int f = 0; f < 2048; f += 4) {
      float4 wv = *(const float4*)(wr + f);
      float4 av = *(const float4*)(acts + f);
      acc += av.x * wv.x + av.y * wv.y + av.z * wv.z + av.w * wv.w;
    }
    out[(size_t)r * 512 + e] = acc;
  }
}

extern "C" void kernel_launch(void* const* d_in, const int* in_sizes, int n_in,
                              void* d_out, int out_size, void* d_ws,
                              size_t ws_size, hipStream_t stream) {
  const float* x  = (const float*)d_in[0];
  const float* ry = (const float*)d_in[1];
  const float* w1 = (const float*)d_in[2];
  const float* b1 = (const float*)d_in[3];
  const float* w2 = (const float*)d_in[4];
  const float* b2 = (const float*)d_in[5];
  float* out = (float*)d_out;

  const size_t w2t_bytes = (size_t)4 * 64 * 4096 * 2;  // 2 MiB
  const size_t w1t_bytes = (size_t)2048 * 32 * 2;      // 128 KiB
  if (ws_size < w2t_bytes + w1t_bytes) {
    k_naive<<<dim3(16384), dim3(256), 0, stream>>>(x, ry, w1, b1, w2, b2, out);
    return;
  }

  unsigned short* w2t = (unsigned short*)d_ws;
  unsigned short* w1t = (unsigned short*)((char*)d_ws + w2t_bytes);

  k_cvt<<<dim3(136), dim3(256), 0, stream>>>(w2, w1, b1, w2t, w1t);
  k_fused<<<dim3(1024), dim3(256), 0, stream>>>(x, ry, w1t, w2t, b2, out);
  (void)in_sizes; (void)n_in; (void)out_size;
}

// Round 6
// 165.614 us; speedup vs baseline: 2.0767x; 1.4054x over previous
//
#include <hip/hip_runtime.h>
#include <cstdint>
#include <cstddef>

// B=8,S=2048,E=512,FFN=2048,Q=8 -> fc2 GEMM: M=16384, N=512, K=2048.
// Fully fused, zero LDS, zero K-loop barriers (R4 trick, numerics verified).
// R5: fragment-ordered weight tiles (coalesced 1-KB wave reads).
// R6: 2 m-tiles per wave (20 MFMA per 10 loads, was 10/10) + explicit
// register double-buffer of next-iteration fragments (aw issued before bf so
// fc1's waitcnt leaves the 8 B-loads in flight).
//
// w2t[nt][kt][nl][quad][e]  (nt<4, kt<64, nl<128, quad<4, e<8) bf16, 2 MiB
//   = w2[nt*128+nl][kt*32+quad*8+e]
// w1t[kt][i][fr][quad][e]   (kt<64, i<2, fr<16, quad<4, e<8)  bf16, 128 KiB
//   = fc1 A-frag for f = kt*32 + 8*(fr>>2)+(fr&3) + 4*i:
//     quad0 = w1[f][0..7], quad1 = {b1[f],0...}, quad2/3 = 0
//     (row permutation makes fc1's D-frag bit-identical to fc2's A-frag)

typedef __attribute__((ext_vector_type(8))) short s16x8;
typedef __attribute__((ext_vector_type(4))) float f32x4;

__device__ __forceinline__ unsigned short f2bf(float f) {  // RNE
  unsigned int u = __float_as_uint(f);
  unsigned int r = u + 0x7fffu + ((u >> 16) & 1u);
  return (unsigned short)(r >> 16);
}

// two fp32 -> packed bf16 dword (round-half-up; inputs finite)
__device__ __forceinline__ unsigned pk_bf16(float lo, float hi) {
  unsigned ul = __float_as_uint(lo) + 0x8000u;
  unsigned uh = __float_as_uint(hi) + 0x8000u;
  return __builtin_amdgcn_perm(uh, ul, 0x07060302u);  // [hi16(uh)|hi16(ul)]
}

__device__ __forceinline__ s16x8 u4s(uint4 u) {
  union { uint4 a; s16x8 b; } c; c.a = u; return c.b;
}

// fc1 for one m-tile: aw1/aw2 = permuted W1 rows, bz = z-fragment.
// Returns the fc2 A-operand fragment (relu'd, bf16-packed).
__device__ __forceinline__ s16x8 make_a(s16x8 aw1, s16x8 aw2, s16x8 bz) {
  const f32x4 zero4 = (f32x4){0.f, 0.f, 0.f, 0.f};
  f32x4 p1 = __builtin_amdgcn_mfma_f32_16x16x32_bf16(aw1, bz, zero4, 0, 0, 0);
  f32x4 p2 = __builtin_amdgcn_mfma_f32_16x16x32_bf16(aw2, bz, zero4, 0, 0, 0);
  uint4 u;
  u.x = pk_bf16(fmaxf(p1[0], 0.f), fmaxf(p1[1], 0.f));
  u.y = pk_bf16(fmaxf(p1[2], 0.f), fmaxf(p1[3], 0.f));
  u.z = pk_bf16(fmaxf(p2[0], 0.f), fmaxf(p2[1], 0.f));
  u.w = pk_bf16(fmaxf(p2[2], 0.f), fmaxf(p2[3], 0.f));
  return u4s(u);
}

// ---------------------------------------------------------------------------
// Setup/retile. bid<128: w2 -> w2t. bid>=128 (8 blocks): w1,b1 -> w1t.
// ---------------------------------------------------------------------------
__global__ __launch_bounds__(256) void k_cvt(const float* __restrict__ w2,
                                             const float* __restrict__ w1,
                                             const float* __restrict__ b1,
                                             unsigned short* __restrict__ w2t,
                                             unsigned short* __restrict__ w1t) {
  const int bid = blockIdx.x, t = threadIdx.x;
  if (bid < 128) {
    const int tid = bid * 256 + t;
    const int n = tid >> 6, kt = tid & 63;
    const float* src = w2 + (size_t)n * 2048 + kt * 32;
    unsigned short* dst =
        w2t + ((size_t)(n >> 7) * 64 + kt) * 4096 + (n & 127) * 32;
#pragma unroll
    for (int g = 0; g < 4; ++g) {
      float4 v0 = *(const float4*)(src + g * 8);
      float4 v1 = *(const float4*)(src + g * 8 + 4);
      uint4 p;
      p.x = f2bf(v0.x) | ((unsigned)f2bf(v0.y) << 16);
      p.y = f2bf(v0.z) | ((unsigned)f2bf(v0.w) << 16);
      p.z = f2bf(v1.x) | ((unsigned)f2bf(v1.y) << 16);
      p.w = f2bf(v1.z) | ((unsigned)f2bf(v1.w) << 16);
      *(uint4*)(dst + g * 8) = p;
    }
  } else {
    const int idx = (bid - 128) * 256 + t;  // 0..2047 = kt*32 + i*16 + fr
    const int kt = idx >> 5, rem = idx & 31, i = rem >> 4, fr = rem & 15;
    const int f = kt * 32 + 8 * (fr >> 2) + (fr & 3) + 4 * i;
    const float* wr = w1 + (size_t)f * 8;
    float4 a = *(const float4*)wr;
    float4 b = *(const float4*)(wr + 4);
    uint4 q0;
    q0.x = f2bf(a.x) | ((unsigned)f2bf(a.y) << 16);
    q0.y = f2bf(a.z) | ((unsigned)f2bf(a.w) << 16);
    q0.z = f2bf(b.x) | ((unsigned)f2bf(b.y) << 16);
    q0.w = f2bf(b.z) | ((unsigned)f2bf(b.w) << 16);
    uint4 q1 = {(unsigned)f2bf(b1[f]), 0u, 0u, 0u};
    uint4 zz = {0u, 0u, 0u, 0u};
    unsigned short* dst = w1t + (size_t)idx * 32;
    *(uint4*)dst = q0;
    *(uint4*)(dst + 8) = q1;
    *(uint4*)(dst + 16) = zz;
    *(uint4*)(dst + 24) = zz;
  }
}

// ---------------------------------------------------------------------------
// Fused kernel. Block = 128m x 128n, 4 waves, each wave 32m x 128n
// (2 m-tiles). Grid = 128 mt * 4 nt = 512 blocks (2/CU).
// ---------------------------------------------------------------------------
__global__ __launch_bounds__(256) void k_fused(
    const float* __restrict__ x, const float* __restrict__ ry,
    const unsigned short* __restrict__ w1t, const unsigned short* __restrict__ w2t,
    const float* __restrict__ b2, float* __restrict__ out) {
  const int t = threadIdx.x;
  const int lane = t & 63;
  const int w = t >> 6;
  const int fr = lane & 15;
  const int quad = lane >> 4;
  const int mt = blockIdx.x & 127;
  const int nt = blockIdx.x >> 7;
  const int c0 = nt * 128;
  const int m0 = mt * 128 + w * 32;  // wave's 32-row base

  // ---- z B-fragments (kt-invariant), one per m-tile:
  //   quad0: z[m][0..7]; quad1: {1.0, 0..} (b1 slot); quads 2,3: 0.
  float4 ra = *(const float4*)ry;
  float4 rb = *(const float4*)(ry + 4);
  const float cr0 = __cosf(ra.x), cr1 = __cosf(ra.y), cr2 = __cosf(ra.z),
              cr3 = __cosf(ra.w), cr4 = __cosf(rb.x), cr5 = __cosf(rb.y),
              cr6 = __cosf(rb.z), cr7 = __cosf(rb.w);
  s16x8 bz[2];
#pragma unroll
  for (int i = 0; i < 2; ++i) {
    const float* xr = x + (size_t)(m0 + i * 16 + fr) * 512;
    float4 xa = *(const float4*)xr;
    float4 xb = *(const float4*)(xr + 4);
    unsigned zd0 = f2bf(__cosf(xa.x) * cr0) |
                   ((unsigned)f2bf(__cosf(xa.y) * cr1) << 16);
    unsigned zd1 = f2bf(__cosf(xa.z) * cr2) |
                   ((unsigned)f2bf(__cosf(xa.w) * cr3) << 16);
    unsigned zd2 = f2bf(__cosf(xb.x) * cr4) |
                   ((unsigned)f2bf(__cosf(xb.y) * cr5) << 16);
    unsigned zd3 = f2bf(__cosf(xb.z) * cr6) |
                   ((unsigned)f2bf(__cosf(xb.w) * cr7) << 16);
    uint4 bzu;
    bzu.x = (quad == 0) ? zd0 : ((quad == 1) ? 0x00003F80u : 0u);
    bzu.y = (quad == 0) ? zd1 : 0u;
    bzu.z = (quad == 0) ? zd2 : 0u;
    bzu.w = (quad == 0) ? zd3 : 0u;
    bz[i] = u4s(bzu);
  }

  // fragment-ordered pointers (contiguous 1-KB wave reads)
  const unsigned short* pW = w1t + fr * 32 + quad * 8;                 // +1024/kt
  const unsigned short* pB = w2t + (size_t)nt * 64 * 4096 + fr * 32 + quad * 8;

  f32x4 acc[2][8];
#pragma unroll
  for (int i = 0; i < 2; ++i)
#pragma unroll
    for (int j = 0; j < 8; ++j) acc[i][j] = (f32x4){0.f, 0.f, 0.f, 0.f};

  // prologue: fragments for kt=0
  s16x8 aw1c = *(const s16x8*)pW;
  s16x8 aw2c = *(const s16x8*)(pW + 512);
  s16x8 bfc[8];
#pragma unroll
  for (int j = 0; j < 8; ++j) bfc[j] = *(const s16x8*)(pB + j * 512);

  for (int kt = 0; kt < 64; ++kt) {
    const int adv = (kt < 63) ? 1 : 0;  // last iter: redundant reload, no OOB
    const unsigned short* pWn = pW + adv * 1024;
    const unsigned short* pBn = pB + adv * 4096;

    // fc1 for kt: waits only on aw (issued before bf last iter -> vmcnt(8))
    s16x8 af0 = make_a(aw1c, aw2c, bz[0]);
    s16x8 af1 = make_a(aw1c, aw2c, bz[1]);

    // issue next-iteration loads: aw FIRST, then bf (in-order vmcnt slack)
    s16x8 aw1n = *(const s16x8*)pWn;
    s16x8 aw2n = *(const s16x8*)(pWn + 512);
    s16x8 bfn[8];
#pragma unroll
    for (int j = 0; j < 8; ++j) bfn[j] = *(const s16x8*)(pBn + j * 512);

    // fc2: 16 MFMA on registers already resident
#pragma unroll
    for (int j = 0; j < 8; ++j) {
      acc[0][j] = __builtin_amdgcn_mfma_f32_16x16x32_bf16(af0, bfc[j],
                                                          acc[0][j], 0, 0, 0);
      acc[1][j] = __builtin_amdgcn_mfma_f32_16x16x32_bf16(af1, bfc[j],
                                                          acc[1][j], 0, 0, 0);
    }

    // rotate
    aw1c = aw1n;
    aw2c = aw2n;
#pragma unroll
    for (int j = 0; j < 8; ++j) bfc[j] = bfn[j];
    pW = pWn;
    pB = pBn;
  }

  // epilogue: fc2 D: lane(fr,quad) holds D[m-local=quad*4+rr][n-local=fr]
  float bias[8];
#pragma unroll
  for (int j = 0; j < 8; ++j) bias[j] = b2[c0 + j * 16 + fr];
#pragma unroll
  for (int i = 0; i < 2; ++i) {
    const int mrow = m0 + i * 16 + quad * 4;
#pragma unroll
    for (int rr = 0; rr < 4; ++rr) {
      float* orow = out + (size_t)(mrow + rr) * 512 + c0;
#pragma unroll
      for (int j = 0; j < 8; ++j) orow[j * 16 + fr] = acc[i][j][rr] + bias[j];
    }
  }
}

// ---------------------------------------------------------------------------
// Emergency fallback if ws < ~2.2 MB: fused fp32, 1 row/block (slow, correct).
// ---------------------------------------------------------------------------
__global__ __launch_bounds__(256) void k_naive(
    const float* __restrict__ x, const float* __restrict__ ry,
    const float* __restrict__ w1, const float* __restrict__ b1,
    const float* __restrict__ w2, const float* __restrict__ b2,
    float* __restrict__ out) {
  __shared__ float zsh[8];
  __shared__ float acts[2048];
  const int r = blockIdx.x;
  const int t = threadIdx.x;
  if (t < 8) zsh[t] = __cosf(x[(size_t)r * 512 + t]) * __cosf(ry[t]);
  __syncthreads();
  float z[8];
#pragma unroll
  for (int q = 0; q < 8; ++q) z[q] = zsh[q];
#pragma unroll
  for (int i = 0; i < 8; ++i) {
    const int f = t * 8 + i;
    const float* wr = w1 + (size_t)f * 8;
    float4 a = *(const float4*)wr;
    float4 b = *(const float4*)(wr + 4);
    float h = b1[f] + z[0] * a.x + z[1] * a.y + z[2] * a.z + z[3] * a.w +
              z[4] * b.x + z[5] * b.y + z[6] * b.z + z[7] * b.w;
    acts[f] = fmaxf(h, 0.0f);
  }
  __syncthreads();
  for (int ee = 0; ee < 2; ++ee) {
    const int e = t + ee * 256;
    const float* wr = w2 + (size_t)e * 2048;
    float acc = b2[e];
    for (int f = 0; f < 2048; f += 4) {
      float4 wv = *(const float4*)(wr + f);
      float4 av = *(const float4*)(acts + f);
      acc += av.x * wv.x + av.y * wv.y + av.z * wv.z + av.w * wv.w;
    }
    out[(size_t)r * 512 + e] = acc;
  }
}

extern "C" void kernel_launch(void* const* d_in, const int* in_sizes, int n_in,
                              void* d_out, int out_size, void* d_ws,
                              size_t ws_size, hipStream_t stream) {
  const float* x  = (const float*)d_in[0];
  const float* ry = (const float*)d_in[1];
  const float* w1 = (const float*)d_in[2];
  const float* b1 = (const float*)d_in[3];
  const float* w2 = (const float*)d_in[4];
  const float* b2 = (const float*)d_in[5];
  float* out = (float*)d_out;

  const size_t w2t_bytes = (size_t)4 * 64 * 4096 * 2;  // 2 MiB
  const size_t w1t_bytes = (size_t)2048 * 32 * 2;      // 128 KiB
  if (ws_size < w2t_bytes + w1t_bytes) {
    k_naive<<<dim3(16384), dim3(256), 0, stream>>>(x, ry, w1, b1, w2, b2, out);
    return;
  }

  unsigned short* w2t = (unsigned short*)d_ws;
  unsigned short* w1t = (unsigned short*)((char*)d_ws + w2t_bytes);

  k_cvt<<<dim3(136), dim3(256), 0, stream>>>(w2, w1, b1, w2t, w1t);
  k_fused<<<dim3(512), dim3(256), 0, stream>>>(x, ry, w1t, w2t, b2, out);
  (void)in_sizes; (void)n_in; (void)out_size;
}